// Round 10
// baseline (314.994 us; speedup 1.0000x reference)
//
#include <hip/hip_runtime.h>
#include <hip/hip_bf16.h>

#define NNODES 50000
#define MT 3125              // NNODES / 16 row-tiles
typedef __hip_bfloat16 bf16;
typedef __attribute__((ext_vector_type(8))) short bf16x8;  // 8 bf16 (4 VGPRs)
typedef __attribute__((ext_vector_type(4))) float f32x4;   // 4 f32 acc

__device__ __forceinline__ void unpack2(unsigned w, float& lo, float& hi){
  lo = __uint_as_float(w << 16);
  hi = __uint_as_float(w & 0xffff0000u);
}
__device__ __forceinline__ short f2bf(float f){
  union { __hip_bfloat16 h; short s; } u; u.h = __float2bfloat16(f); return u.s;
}
__device__ __forceinline__ float lrelu(float v){ return v > 0.f ? v : 0.2f * v; }

// ---------------- pack weights -> B-fragment bf16 ----------------
__global__ __launch_bounds__(256)
void cvt_w_k(const float* __restrict__ W1, const float* __restrict__ Wmu,
             const float* __restrict__ Wls, bf16x8* __restrict__ Bp1,
             bf16x8* __restrict__ Bp2){
  int t = blockIdx.x * 256 + threadIdx.x;
  if (t < 4096){
    int lane = t & 63, ct = (t >> 6) & 15, kt = t >> 10;
    int k0 = kt * 32 + (lane >> 4) * 8, col = ct * 16 + (lane & 15);
    bf16x8 o;
    #pragma unroll
    for (int j = 0; j < 8; j++) o[j] = f2bf(W1[(size_t)(k0 + j) * 256 + col]);
    Bp1[t] = o;
  } else if (t < 8192){
    int u = t - 4096;
    int lane = u & 63, ct = (u >> 6) & 7, kt = u >> 9;
    int k0 = kt * 32 + (lane >> 4) * 8, col = ct * 16 + (lane & 15);
    const float* W = (col < 64) ? Wmu : Wls;
    int cc = col & 63;
    bf16x8 o;
    #pragma unroll
    for (int j = 0; j < 8; j++) o[j] = f2bf(W[(size_t)(k0 + j) * 64 + cc]);
    Bp2[u] = o;
  }
}

// ------- MFMA GEMM 1 (reads f32 x directly) + fused alpha -------
__global__ __launch_bounds__(256)
void gemm1_mfma(const float* __restrict__ x, const bf16x8* __restrict__ Bp,
                const float* __restrict__ aS, const float* __restrict__ aD,
                bf16* __restrict__ Y, float* __restrict__ as1, float* __restrict__ ad1){
  int rt = blockIdx.x;
  int w = threadIdx.x >> 6, lane = threadIdx.x & 63;
  const float* xr = x + (size_t)(rt * 16 + (lane & 15)) * 128 + (lane >> 4) * 8;
  f32x4 z = {0.f, 0.f, 0.f, 0.f};
  f32x4 acc[4] = {z, z, z, z};
  for (int kt = 0; kt < 4; kt++){
    float4 v0 = *(const float4*)(xr + kt * 32);
    float4 v1 = *(const float4*)(xr + kt * 32 + 4);
    bf16x8 a;
    a[0] = f2bf(v0.x); a[1] = f2bf(v0.y); a[2] = f2bf(v0.z); a[3] = f2bf(v0.w);
    a[4] = f2bf(v1.x); a[5] = f2bf(v1.y); a[6] = f2bf(v1.z); a[7] = f2bf(v1.w);
    #pragma unroll
    for (int c = 0; c < 4; c++){
      bf16x8 b = Bp[(size_t)(kt * 16 + w * 4 + c) * 64 + lane];
      acc[c] = __builtin_amdgcn_mfma_f32_16x16x32_bf16(a, b, acc[c], 0, 0, 0);
    }
  }
  int row0 = rt * 16 + (lane >> 4) * 4;
  #pragma unroll
  for (int c = 0; c < 4; c++){
    int col = w * 64 + c * 16 + (lane & 15);
    #pragma unroll
    for (int i = 0; i < 4; i++)
      Y[(size_t)(row0 + i) * 256 + col] = __float2bfloat16(acc[c][i]);
  }
  float aSv[4], aDv[4];
  #pragma unroll
  for (int c = 0; c < 4; c++){
    int col = c * 16 + (lane & 15);
    aSv[c] = aS[w * 64 + col];
    aDv[c] = aD[w * 64 + col];
  }
  #pragma unroll
  for (int i = 0; i < 4; i++){
    float s1 = 0.f, s2 = 0.f;
    #pragma unroll
    for (int c = 0; c < 4; c++){
      s1 = fmaf(acc[c][i], aSv[c], s1);
      s2 = fmaf(acc[c][i], aDv[c], s2);
    }
    #pragma unroll
    for (int o = 1; o < 16; o <<= 1){
      s1 += __shfl_xor(s1, o);
      s2 += __shfl_xor(s2, o);
    }
    if ((lane & 15) == 0){
      int node = row0 + i;
      as1[node * 4 + w] = s1;
      ad1[node * 4 + w] = s2;
    }
  }
}

// ------- MFMA GEMM 2: one wave = one row-tile, computes BOTH branches -------
// A-frags read once; 8 MFMA cols (4 mu + 4 ls); fused alphas for both branches
__global__ __launch_bounds__(256)
void gemm2_mfma(const bf16x8* __restrict__ Ap, const bf16x8* __restrict__ Bp,
                const float* __restrict__ aSmu, const float* __restrict__ aDmu,
                const float* __restrict__ aSls, const float* __restrict__ aDls,
                bf16* __restrict__ Ymu, bf16* __restrict__ Yls,
                float* __restrict__ as2m, float* __restrict__ ad2m,
                float* __restrict__ as2l, float* __restrict__ ad2l){
  int w = threadIdx.x >> 6, lane = threadIdx.x & 63;
  int rt = blockIdx.x * 4 + w;
  if (rt >= MT) return;
  f32x4 z = {0.f, 0.f, 0.f, 0.f};
  f32x4 acc[8] = {z, z, z, z, z, z, z, z};   // 0-3 mu, 4-7 ls
  for (int kt = 0; kt < 8; kt++){
    bf16x8 a = Ap[(size_t)(rt * 8 + kt) * 64 + lane];
    #pragma unroll
    for (int c = 0; c < 8; c++){
      bf16x8 b = Bp[(size_t)(kt * 8 + c) * 64 + lane];
      acc[c] = __builtin_amdgcn_mfma_f32_16x16x32_bf16(a, b, acc[c], 0, 0, 0);
    }
  }
  int row0 = rt * 16 + (lane >> 4) * 4;
  #pragma unroll
  for (int c = 0; c < 4; c++){
    int col = c * 16 + (lane & 15);
    #pragma unroll
    for (int i = 0; i < 4; i++){
      Ymu[(size_t)(row0 + i) * 64 + col] = __float2bfloat16(acc[c][i]);
      Yls[(size_t)(row0 + i) * 64 + col] = __float2bfloat16(acc[4 + c][i]);
    }
  }
  float aSm[4], aDm[4], aSl[4], aDl[4];
  #pragma unroll
  for (int c = 0; c < 4; c++){
    int col = c * 16 + (lane & 15);
    aSm[c] = aSmu[col]; aDm[c] = aDmu[col];
    aSl[c] = aSls[col]; aDl[c] = aDls[col];
  }
  #pragma unroll
  for (int i = 0; i < 4; i++){
    float s1 = 0.f, s2 = 0.f, s3 = 0.f, s4 = 0.f;
    #pragma unroll
    for (int c = 0; c < 4; c++){
      s1 = fmaf(acc[c][i], aSm[c], s1);
      s2 = fmaf(acc[c][i], aDm[c], s2);
      s3 = fmaf(acc[4 + c][i], aSl[c], s3);
      s4 = fmaf(acc[4 + c][i], aDl[c], s4);
    }
    #pragma unroll
    for (int o = 1; o < 16; o <<= 1){
      s1 += __shfl_xor(s1, o);
      s2 += __shfl_xor(s2, o);
      s3 += __shfl_xor(s3, o);
      s4 += __shfl_xor(s4, o);
    }
    if ((lane & 15) == 0){
      int node = row0 + i;
      as2m[node] = s1; ad2m[node] = s2;
      as2l[node] = s3; ad2l[node] = s4;
    }
  }
}

// ---------------- CSR build ----------------
__global__ __launch_bounds__(256)
void hist_k(const int* __restrict__ ei, int E0, int Etot, int* __restrict__ cnt){
  int e = blockIdx.x * 256 + threadIdx.x;
  if (e >= Etot) return;
  int d = (e < E0) ? ei[E0 + e] : e - E0;
  atomicAdd(&cnt[d], 1);
}

__global__ __launch_bounds__(1024)
void scanA_k(const int* __restrict__ cnt, int* __restrict__ offs,
             int* __restrict__ bsums, int n){
  __shared__ int buf[1024];
  int tid = threadIdx.x;
  int i = blockIdx.x * 1024 + tid;
  int v = (i < n) ? cnt[i] : 0;
  buf[tid] = v; __syncthreads();
  int acc = v;
  for (int off = 1; off < 1024; off <<= 1){
    int t = (tid >= off) ? buf[tid - off] : 0;
    __syncthreads();
    acc += t; buf[tid] = acc;
    __syncthreads();
  }
  if (i < n) offs[i] = acc - v;
  if (tid == 1023) bsums[blockIdx.x] = acc;
}

__global__ void scanB_k(int* __restrict__ bsums, int nb){
  int lane = threadIdx.x;
  int orig = (lane < nb) ? bsums[lane] : 0;
  int v = orig;
  #pragma unroll
  for (int o = 1; o < 64; o <<= 1){
    int t = __shfl_up(v, o);
    if (lane >= o) v += t;
  }
  if (lane < nb) bsums[lane] = v - orig;   // exclusive
}

__global__ __launch_bounds__(256)
void scanC_k(int* __restrict__ offs, const int* __restrict__ bsums,
             int* __restrict__ cursor, int n, int total){
  int i = blockIdx.x * 256 + threadIdx.x;
  if (i < n){
    int v = offs[i] + bsums[i >> 10];
    offs[i] = v;
    cursor[i] = v;
  }
  if (i == 0) offs[n] = total;
}

__global__ __launch_bounds__(256)
void sort_k(const int* __restrict__ ei, int E0, int Etot,
            int* __restrict__ cursor, int* __restrict__ srcs){
  int e = blockIdx.x * 256 + threadIdx.x;
  if (e >= Etot) return;
  int s, d;
  if (e < E0){ s = ei[e]; d = ei[E0 + e]; } else { s = d = e - E0; }
  int pos = atomicAdd(&cursor[d], 1);
  srcs[pos] = s;
}

// ------- aggregation layer 1, HEAD-SPLIT pass: heads {H0, H0+1} -------
// lane: slot = lane>>4 (4 slots), head = H0 + ((lane>>3)&1), octet = lane&7
template<int H0>
__global__ __launch_bounds__(256)
void gat_aggr1_k(const int* __restrict__ offs, const int* __restrict__ srcs,
                 const float* __restrict__ as, const float* __restrict__ ad,
                 const bf16* __restrict__ h, const float* __restrict__ b,
                 bf16x8* __restrict__ Ap2, int n){
  int node = blockIdx.x * 4 + (threadIdx.x >> 6);
  if (node >= n) return;
  int lane = threadIdx.x & 63;
  int beg = offs[node], end = offs[node + 1];
  int hP   = H0 + ((lane >> 3) & 1);
  int oct  = lane & 7;
  int slot = lane >> 4;
  float advP = ad[node * 4 + hP];
  float m = -1e30f, s = 0.f;
  float acc[8];
  #pragma unroll
  for (int i = 0; i < 8; i++) acc[i] = 0.f;
  #pragma unroll 4
  for (int j0 = beg; j0 < end; j0 += 4){
    int j = j0 + slot;
    if (j < end){
      int si = srcs[j];
      float e = lrelu(as[si * 4 + hP] + advP);
      float p;
      if (e > m){
        float f = __expf(m - e);
        s = s * f + 1.f;
        #pragma unroll
        for (int i = 0; i < 8; i++) acc[i] *= f;
        m = e; p = 1.f;
      } else {
        p = __expf(e - m);
        s += p;
      }
      uint4 dw = *(const uint4*)(h + (size_t)si * 256 + hP * 64 + oct * 8);
      float lo, hi;
      unpack2(dw.x, lo, hi); acc[0] = fmaf(lo, p, acc[0]); acc[1] = fmaf(hi, p, acc[1]);
      unpack2(dw.y, lo, hi); acc[2] = fmaf(lo, p, acc[2]); acc[3] = fmaf(hi, p, acc[3]);
      unpack2(dw.z, lo, hi); acc[4] = fmaf(lo, p, acc[4]); acc[5] = fmaf(hi, p, acc[5]);
      unpack2(dw.w, lo, hi); acc[6] = fmaf(lo, p, acc[6]); acc[7] = fmaf(hi, p, acc[7]);
    }
  }
  // fold the 4 slots (lane bits 4,5) with rescale
  #pragma unroll
  for (int off = 16; off <= 32; off <<= 1){
    float mo = __shfl_xor(m, off);
    float so = __shfl_xor(s, off);
    float nm = fmaxf(m, mo);
    float f  = __expf(m - nm);
    float fo = __expf(mo - nm);
    s = s * f + so * fo;
    #pragma unroll
    for (int i = 0; i < 8; i++)
      acc[i] = acc[i] * f + __shfl_xor(acc[i], off) * fo;
    m = nm;
  }
  if (lane < 16){
    float inv = 1.f / (s + 1e-16f);
    bf16x8 o;
    #pragma unroll
    for (int i = 0; i < 8; i++){
      float vv = acc[i] * inv + b[hP * 64 + oct * 8 + i];
      o[i] = f2bf(vv > 0.f ? vv : 0.f);
    }
    int O = hP * 8 + oct;
    int kt = O >> 2, g = O & 3;
    int rt = node >> 4, r = node & 15;
    Ap2[(size_t)(rt * 8 + kt) * 64 + g * 16 + r] = o;
  }
}

// ------- aggregation mu OR logstd (single branch per launch) -------
// lane: slot = lane>>3 (8 slots), octet = lane&7
__global__ __launch_bounds__(256)
void gat_aggr2_k(const int* __restrict__ offs, const int* __restrict__ srcs,
                 const float* __restrict__ asB, const float* __restrict__ adB,
                 const bf16* __restrict__ hB, const float* __restrict__ bB,
                 float* __restrict__ outB, int n){
  int node = blockIdx.x * 4 + (threadIdx.x >> 6);
  if (node >= n) return;
  int lane = threadIdx.x & 63;
  int beg = offs[node], end = offs[node + 1];
  int oct  = lane & 7;
  int slot = lane >> 3;
  float adv = adB[node];
  float m = -1e30f, s = 0.f;
  float acc[8];
  #pragma unroll
  for (int i = 0; i < 8; i++) acc[i] = 0.f;
  #pragma unroll 2
  for (int j0 = beg; j0 < end; j0 += 8){
    int j = j0 + slot;
    if (j < end){
      int si = srcs[j];
      float e = lrelu(asB[si] + adv);
      float p;
      if (e > m){
        float f = __expf(m - e);
        s = s * f + 1.f;
        #pragma unroll
        for (int i = 0; i < 8; i++) acc[i] *= f;
        m = e; p = 1.f;
      } else {
        p = __expf(e - m);
        s += p;
      }
      uint4 dw = *(const uint4*)(hB + (size_t)si * 64 + oct * 8);
      float lo, hi;
      unpack2(dw.x, lo, hi); acc[0] = fmaf(lo, p, acc[0]); acc[1] = fmaf(hi, p, acc[1]);
      unpack2(dw.y, lo, hi); acc[2] = fmaf(lo, p, acc[2]); acc[3] = fmaf(hi, p, acc[3]);
      unpack2(dw.z, lo, hi); acc[4] = fmaf(lo, p, acc[4]); acc[5] = fmaf(hi, p, acc[5]);
      unpack2(dw.w, lo, hi); acc[6] = fmaf(lo, p, acc[6]); acc[7] = fmaf(hi, p, acc[7]);
    }
  }
  // fold the 8 slots (lane bits 3,4,5) with rescale
  #pragma unroll
  for (int off = 8; off <= 32; off <<= 1){
    float mo = __shfl_xor(m, off);
    float so = __shfl_xor(s, off);
    float nm = fmaxf(m, mo);
    float f  = __expf(m - nm);
    float fo = __expf(mo - nm);
    s = s * f + so * fo;
    #pragma unroll
    for (int i = 0; i < 8; i++)
      acc[i] = acc[i] * f + __shfl_xor(acc[i], off) * fo;
    m = nm;
  }
  if (lane < 8){
    float inv = 1.f / (s + 1e-16f);
    float v[8];
    #pragma unroll
    for (int i = 0; i < 8; i++) v[i] = acc[i] * inv + bB[oct * 8 + i];
    float* op = outB + (size_t)node * 64 + oct * 8;
    *(float4*)op       = make_float4(v[0], v[1], v[2], v[3]);
    *(float4*)(op + 4) = make_float4(v[4], v[5], v[6], v[7]);
  }
}

extern "C" void kernel_launch(void* const* d_in, const int* in_sizes, int n_in,
                              void* d_out, int out_size, void* d_ws, size_t ws_size,
                              hipStream_t stream){
  const float* x    = (const float*)d_in[0];
  const int*   ei   = (const int*)d_in[1];
  const float* W1   = (const float*)d_in[2];
  const float* aS1  = (const float*)d_in[3];
  const float* aD1  = (const float*)d_in[4];
  const float* b1   = (const float*)d_in[5];
  const float* Wmu  = (const float*)d_in[6];
  const float* aSmu = (const float*)d_in[7];
  const float* aDmu = (const float*)d_in[8];
  const float* bmu  = (const float*)d_in[9];
  const float* Wls  = (const float*)d_in[10];
  const float* aSls = (const float*)d_in[11];
  const float* aDls = (const float*)d_in[12];
  const float* bls  = (const float*)d_in[13];

  const int N    = NNODES;
  const int E0   = in_sizes[1] / 2;
  const int Etot = E0 + N;

  // ---- workspace layout (float-unit offsets; bf16x8 arrays 16B-aligned) ----
  float* ws = (float*)d_ws;
  bf16x8* Ap2  = (bf16x8*)(ws);                 // [0, 6.4M): layer-1 out, packed A-frag
  bf16*   h1bf = (bf16*)(ws + 6400000);         // [6.4M, 12.8M): 12.8M bf16 row-major
  bf16*   h2mu = (bf16*)(ws + 12800000);        // [12.8M, 14.4M): 3.2M bf16
  bf16*   h2ls = (bf16*)(ws + 14400000);        // [14.4M, 16M)
  float*  as1  = ws + 16000000;                 // 200K
  float*  ad1  = ws + 16200000;                 // 200K
  float*  as2m = ws + 16400000;                 // 50K each
  float*  ad2m = ws + 16450000;
  float*  as2l = ws + 16500000;
  float*  ad2l = ws + 16550000;
  int* cnt    = (int*)(ws + 16600000);          // 50K
  int* cursor = (int*)(ws + 16650000);          // 50K
  int* offs   = (int*)(ws + 16700000);          // 50001
  int* srcs   = (int*)(ws + 16750016);          // 850K
  int* bsums  = (int*)(ws + 17600016);          // 64
  bf16x8* Bp1 = (bf16x8*)(ws + 17600080);       // 32768 bf16 = 16384 floats
  bf16x8* Bp2 = (bf16x8*)(ws + 17616464);       // 32768 bf16

  float* outmu = (float*)d_out;
  float* outls = (float*)d_out + 3200000;

  const int egrid = (Etot + 255) / 256;

  // ---- CSR build (shared by all 3 convs) ----
  hipMemsetAsync(cnt, 0, 50000 * sizeof(int), stream);
  hist_k<<<egrid, 256, 0, stream>>>(ei, E0, Etot, cnt);
  scanA_k<<<(N + 1023) / 1024, 1024, 0, stream>>>(cnt, offs, bsums, N);
  scanB_k<<<1, 64, 0, stream>>>(bsums, (N + 1023) / 1024);
  scanC_k<<<(N + 256) / 256, 256, 0, stream>>>(offs, bsums, cursor, N, Etot);
  sort_k<<<egrid, 256, 0, stream>>>(ei, E0, Etot, cursor, srcs);

  // ---- weight packing for MFMA ----
  cvt_w_k<<<32, 256, 0, stream>>>(W1, Wmu, Wls, Bp1, Bp2);

  // ---- layer 1: GATConv(128 -> 4x64, concat) + bias + ReLU ----
  gemm1_mfma<<<MT, 256, 0, stream>>>(x, Bp1, aS1, aD1, h1bf, as1, ad1);
  gat_aggr1_k<0><<<(N + 3) / 4, 256, 0, stream>>>(offs, srcs, as1, ad1, h1bf, b1, Ap2, N);
  gat_aggr1_k<2><<<(N + 3) / 4, 256, 0, stream>>>(offs, srcs, as1, ad1, h1bf, b1, Ap2, N);

  // ---- layers mu & logstd: GATConv(256 -> 1x64) + bias ----
  gemm2_mfma<<<(MT + 3) / 4, 256, 0, stream>>>(Ap2, Bp2, aSmu, aDmu, aSls, aDls,
                                               h2mu, h2ls, as2m, ad2m, as2l, ad2l);
  gat_aggr2_k<<<(N + 3) / 4, 256, 0, stream>>>(offs, srcs, as2m, ad2m, h2mu, bmu, outmu, N);
  gat_aggr2_k<<<(N + 3) / 4, 256, 0, stream>>>(offs, srcs, as2l, ad2l, h2ls, bls, outls, N);
}

// Round 11
// 241.299 us; speedup vs baseline: 1.3054x; 1.3054x over previous
//
#include <hip/hip_runtime.h>
#include <hip/hip_bf16.h>

#define NNODES 50000
#define MT 3125              // NNODES / 16 row-tiles
#define NB 196               // ceil(NNODES / 256) dst-buckets
typedef __hip_bfloat16 bf16;
typedef __attribute__((ext_vector_type(8))) short bf16x8;  // 8 bf16 (4 VGPRs)
typedef __attribute__((ext_vector_type(4))) float f32x4;   // 4 f32 acc

__device__ __forceinline__ void unpack2(unsigned w, float& lo, float& hi){
  lo = __uint_as_float(w << 16);
  hi = __uint_as_float(w & 0xffff0000u);
}
__device__ __forceinline__ short f2bf(float f){
  union { __hip_bfloat16 h; short s; } u; u.h = __float2bfloat16(f); return u.s;
}
__device__ __forceinline__ float lrelu(float v){ return v > 0.f ? v : 0.2f * v; }

// ---------------- pack weights -> B-fragment bf16 ----------------
__global__ __launch_bounds__(256)
void cvt_w_k(const float* __restrict__ W1, const float* __restrict__ Wmu,
             const float* __restrict__ Wls, bf16x8* __restrict__ Bp1,
             bf16x8* __restrict__ Bp2){
  int t = blockIdx.x * 256 + threadIdx.x;
  if (t < 4096){
    int lane = t & 63, ct = (t >> 6) & 15, kt = t >> 10;
    int k0 = kt * 32 + (lane >> 4) * 8, col = ct * 16 + (lane & 15);
    bf16x8 o;
    #pragma unroll
    for (int j = 0; j < 8; j++) o[j] = f2bf(W1[(size_t)(k0 + j) * 256 + col]);
    Bp1[t] = o;
  } else if (t < 8192){
    int u = t - 4096;
    int lane = u & 63, ct = (u >> 6) & 7, kt = u >> 9;
    int k0 = kt * 32 + (lane >> 4) * 8, col = ct * 16 + (lane & 15);
    const float* W = (col < 64) ? Wmu : Wls;
    int cc = col & 63;
    bf16x8 o;
    #pragma unroll
    for (int j = 0; j < 8; j++) o[j] = f2bf(W[(size_t)(k0 + j) * 64 + cc]);
    Bp2[u] = o;
  }
}

// ------- MFMA GEMM 1 (reads f32 x directly) + fused alpha -------
__global__ __launch_bounds__(256)
void gemm1_mfma(const float* __restrict__ x, const bf16x8* __restrict__ Bp,
                const float* __restrict__ aS, const float* __restrict__ aD,
                bf16* __restrict__ Y, float* __restrict__ as1, float* __restrict__ ad1){
  int rt = blockIdx.x;
  int w = threadIdx.x >> 6, lane = threadIdx.x & 63;
  const float* xr = x + (size_t)(rt * 16 + (lane & 15)) * 128 + (lane >> 4) * 8;
  f32x4 z = {0.f, 0.f, 0.f, 0.f};
  f32x4 acc[4] = {z, z, z, z};
  for (int kt = 0; kt < 4; kt++){
    float4 v0 = *(const float4*)(xr + kt * 32);
    float4 v1 = *(const float4*)(xr + kt * 32 + 4);
    bf16x8 a;
    a[0] = f2bf(v0.x); a[1] = f2bf(v0.y); a[2] = f2bf(v0.z); a[3] = f2bf(v0.w);
    a[4] = f2bf(v1.x); a[5] = f2bf(v1.y); a[6] = f2bf(v1.z); a[7] = f2bf(v1.w);
    #pragma unroll
    for (int c = 0; c < 4; c++){
      bf16x8 b = Bp[(size_t)(kt * 16 + w * 4 + c) * 64 + lane];
      acc[c] = __builtin_amdgcn_mfma_f32_16x16x32_bf16(a, b, acc[c], 0, 0, 0);
    }
  }
  int row0 = rt * 16 + (lane >> 4) * 4;
  #pragma unroll
  for (int c = 0; c < 4; c++){
    int col = w * 64 + c * 16 + (lane & 15);
    #pragma unroll
    for (int i = 0; i < 4; i++)
      Y[(size_t)(row0 + i) * 256 + col] = __float2bfloat16(acc[c][i]);
  }
  float aSv[4], aDv[4];
  #pragma unroll
  for (int c = 0; c < 4; c++){
    int col = c * 16 + (lane & 15);
    aSv[c] = aS[w * 64 + col];
    aDv[c] = aD[w * 64 + col];
  }
  #pragma unroll
  for (int i = 0; i < 4; i++){
    float s1 = 0.f, s2 = 0.f;
    #pragma unroll
    for (int c = 0; c < 4; c++){
      s1 = fmaf(acc[c][i], aSv[c], s1);
      s2 = fmaf(acc[c][i], aDv[c], s2);
    }
    #pragma unroll
    for (int o = 1; o < 16; o <<= 1){
      s1 += __shfl_xor(s1, o);
      s2 += __shfl_xor(s2, o);
    }
    if ((lane & 15) == 0){
      int node = row0 + i;
      as1[node * 4 + w] = s1;
      ad1[node * 4 + w] = s2;
    }
  }
}

// ------- MFMA GEMM 2: one wave = one row-tile, BOTH branches + fused alphas -------
__global__ __launch_bounds__(256)
void gemm2_mfma(const bf16x8* __restrict__ Ap, const bf16x8* __restrict__ Bp,
                const float* __restrict__ aSmu, const float* __restrict__ aDmu,
                const float* __restrict__ aSls, const float* __restrict__ aDls,
                bf16* __restrict__ Ymu, bf16* __restrict__ Yls,
                float* __restrict__ as2m, float* __restrict__ ad2m,
                float* __restrict__ as2l, float* __restrict__ ad2l){
  int w = threadIdx.x >> 6, lane = threadIdx.x & 63;
  int rt = blockIdx.x * 4 + w;
  if (rt >= MT) return;
  f32x4 z = {0.f, 0.f, 0.f, 0.f};
  f32x4 acc[8] = {z, z, z, z, z, z, z, z};   // 0-3 mu, 4-7 ls
  for (int kt = 0; kt < 8; kt++){
    bf16x8 a = Ap[(size_t)(rt * 8 + kt) * 64 + lane];
    #pragma unroll
    for (int c = 0; c < 8; c++){
      bf16x8 b = Bp[(size_t)(kt * 8 + c) * 64 + lane];
      acc[c] = __builtin_amdgcn_mfma_f32_16x16x32_bf16(a, b, acc[c], 0, 0, 0);
    }
  }
  int row0 = rt * 16 + (lane >> 4) * 4;
  #pragma unroll
  for (int c = 0; c < 4; c++){
    int col = c * 16 + (lane & 15);
    #pragma unroll
    for (int i = 0; i < 4; i++){
      Ymu[(size_t)(row0 + i) * 64 + col] = __float2bfloat16(acc[c][i]);
      Yls[(size_t)(row0 + i) * 64 + col] = __float2bfloat16(acc[4 + c][i]);
    }
  }
  float aSm[4], aDm[4], aSl[4], aDl[4];
  #pragma unroll
  for (int c = 0; c < 4; c++){
    int col = c * 16 + (lane & 15);
    aSm[c] = aSmu[col]; aDm[c] = aDmu[col];
    aSl[c] = aSls[col]; aDl[c] = aDls[col];
  }
  #pragma unroll
  for (int i = 0; i < 4; i++){
    float s1 = 0.f, s2 = 0.f, s3 = 0.f, s4 = 0.f;
    #pragma unroll
    for (int c = 0; c < 4; c++){
      s1 = fmaf(acc[c][i], aSm[c], s1);
      s2 = fmaf(acc[c][i], aDm[c], s2);
      s3 = fmaf(acc[4 + c][i], aSl[c], s3);
      s4 = fmaf(acc[4 + c][i], aDl[c], s4);
    }
    #pragma unroll
    for (int o = 1; o < 16; o <<= 1){
      s1 += __shfl_xor(s1, o);
      s2 += __shfl_xor(s2, o);
      s3 += __shfl_xor(s3, o);
      s4 += __shfl_xor(s4, o);
    }
    if ((lane & 15) == 0){
      int node = row0 + i;
      as2m[node] = s1; ad2m[node] = s2;
      as2l[node] = s3; ad2l[node] = s4;
    }
  }
}

// ================ two-phase LDS bucket CSR build ================
// Phase A: per-block LDS bucket histogram -> global bcnt
__global__ __launch_bounds__(256)
void bhist_k(const int* __restrict__ ei, int E0, int Etot, int* __restrict__ bcnt){
  __shared__ int lh[NB];
  for (int i = threadIdx.x; i < NB; i += 256) lh[i] = 0;
  __syncthreads();
  int base = blockIdx.x * 1024 + threadIdx.x;
  #pragma unroll
  for (int q = 0; q < 4; q++){
    int e = base + q * 256;
    if (e < Etot){
      int d = (e < E0) ? ei[E0 + e] : e - E0;
      atomicAdd(&lh[d >> 8], 1);
    }
  }
  __syncthreads();
  for (int i = threadIdx.x; i < NB; i += 256)
    if (lh[i]) atomicAdd(&bcnt[i], lh[i]);
}

// Phase B: exclusive scan of bucket counts -> bbase, bcur
__global__ __launch_bounds__(256)
void bscan_k(const int* __restrict__ bcnt, int* __restrict__ bbase,
             int* __restrict__ bcur, int total){
  __shared__ int buf[256];
  int t = threadIdx.x;
  int v = (t < NB) ? bcnt[t] : 0;
  buf[t] = v; __syncthreads();
  int acc = v;
  for (int off = 1; off < 256; off <<= 1){
    int x = (t >= off) ? buf[t - off] : 0;
    __syncthreads();
    acc += x; buf[t] = acc; __syncthreads();
  }
  if (t < NB){ int ex = acc - v; bbase[t] = ex; bcur[t] = ex; }
  if (t == 0) bbase[NB] = total;
}

// Phase C: scatter packed edges into bucket regions, block-chunk reserved
__global__ __launch_bounds__(256)
void bscat_k(const int* __restrict__ ei, int E0, int Etot,
             int* __restrict__ bcur, unsigned* __restrict__ buck){
  __shared__ int lh[NB];
  __shared__ int lbase[NB];
  for (int i = threadIdx.x; i < NB; i += 256) lh[i] = 0;
  __syncthreads();
  int base = blockIdx.x * 1024 + threadIdx.x;
  int sA[4], dA[4], rA[4];
  #pragma unroll
  for (int q = 0; q < 4; q++){
    int e = base + q * 256;
    sA[q] = -1;
    if (e < Etot){
      int s, d;
      if (e < E0){ s = ei[e]; d = ei[E0 + e]; } else { s = d = e - E0; }
      sA[q] = s; dA[q] = d;
      rA[q] = atomicAdd(&lh[d >> 8], 1);
    }
  }
  __syncthreads();
  for (int i = threadIdx.x; i < NB; i += 256)
    lbase[i] = lh[i] ? atomicAdd(&bcur[i], lh[i]) : 0;
  __syncthreads();
  #pragma unroll
  for (int q = 0; q < 4; q++){
    if (sA[q] >= 0){
      int bk = dA[q] >> 8;
      buck[lbase[bk] + rA[q]] = ((unsigned)(dA[q] & 255) << 16) | (unsigned)sA[q];
    }
  }
}

// Phase D: per-bucket CSR finalize (offs coalesced, srcs within L2-hot region)
__global__ __launch_bounds__(256)
void bcsr_k(const unsigned* __restrict__ buck, const int* __restrict__ bbase,
            int* __restrict__ offs, int* __restrict__ srcs, int n){
  int b = blockIdx.x;
  int lo = bbase[b], hi = bbase[b + 1];
  __shared__ int eh[256];
  __shared__ int buf[256];
  int t = threadIdx.x;
  eh[t] = 0;
  __syncthreads();
  for (int j = lo + t; j < hi; j += 256)
    atomicAdd(&eh[(buck[j] >> 16) & 255], 1);
  __syncthreads();
  int v = eh[t];
  buf[t] = v; __syncthreads();
  int acc = v;
  for (int off = 1; off < 256; off <<= 1){
    int x = (t >= off) ? buf[t - off] : 0;
    __syncthreads();
    acc += x; buf[t] = acc; __syncthreads();
  }
  int loff = acc - v;   // exclusive within bucket
  int node = b * 256 + t;
  if (node < n) offs[node] = lo + loff;
  if (b == NB - 1 && t == 0) offs[n] = bbase[NB];
  __syncthreads();
  eh[t] = loff;        // reuse as cursors
  __syncthreads();
  for (int j = lo + t; j < hi; j += 256){
    unsigned val = buck[j];
    int dlo = (val >> 16) & 255;
    int rank = atomicAdd(&eh[dlo], 1);
    srcs[lo + rank] = (int)(val & 0xffffu);
  }
}

// ------- fused aggregation, layer 1: one wave/node, single online-softmax pass -------
// slot = lane>>5 (2 slots), head = (lane>>3)&3, octet = lane&7
__global__ __launch_bounds__(256)
void gat_aggr1_k(const int* __restrict__ offs, const int* __restrict__ srcs,
                 const float* __restrict__ as, const float* __restrict__ ad,
                 const bf16* __restrict__ h, const float* __restrict__ b,
                 bf16x8* __restrict__ Ap2, int n){
  int node = blockIdx.x * 4 + (threadIdx.x >> 6);
  if (node >= n) return;
  int lane = threadIdx.x & 63;
  int beg = offs[node], end = offs[node + 1];
  int hP   = (lane >> 3) & 3;
  int oct  = lane & 7;
  int slot = lane >> 5;
  float advP = ad[node * 4 + hP];
  float m = -1e30f, s = 0.f;
  float acc[8];
  #pragma unroll
  for (int i = 0; i < 8; i++) acc[i] = 0.f;
  #pragma unroll 4
  for (int j0 = beg; j0 < end; j0 += 2){
    int j = j0 + slot;
    if (j < end){
      int si = srcs[j];
      float e = lrelu(as[si * 4 + hP] + advP);
      float p;
      if (e > m){
        float f = __expf(m - e);
        s = s * f + 1.f;
        #pragma unroll
        for (int i = 0; i < 8; i++) acc[i] *= f;
        m = e; p = 1.f;
      } else {
        p = __expf(e - m);
        s += p;
      }
      uint4 dw = *(const uint4*)(h + (size_t)si * 256 + hP * 64 + oct * 8);
      float lo, hi;
      unpack2(dw.x, lo, hi); acc[0] = fmaf(lo, p, acc[0]); acc[1] = fmaf(hi, p, acc[1]);
      unpack2(dw.y, lo, hi); acc[2] = fmaf(lo, p, acc[2]); acc[3] = fmaf(hi, p, acc[3]);
      unpack2(dw.z, lo, hi); acc[4] = fmaf(lo, p, acc[4]); acc[5] = fmaf(hi, p, acc[5]);
      unpack2(dw.w, lo, hi); acc[6] = fmaf(lo, p, acc[6]); acc[7] = fmaf(hi, p, acc[7]);
    }
  }
  {
    float mo = __shfl_xor(m, 32);
    float so = __shfl_xor(s, 32);
    float nm = fmaxf(m, mo);
    float f  = __expf(m - nm);
    float fo = __expf(mo - nm);
    s = s * f + so * fo;
    #pragma unroll
    for (int i = 0; i < 8; i++)
      acc[i] = acc[i] * f + __shfl_xor(acc[i], 32) * fo;
  }
  if (lane < 32){
    float inv = 1.f / (s + 1e-16f);
    bf16x8 o;
    #pragma unroll
    for (int i = 0; i < 8; i++){
      float vv = acc[i] * inv + b[lane * 8 + i];
      o[i] = f2bf(vv > 0.f ? vv : 0.f);
    }
    int kt = lane >> 2, g = lane & 3;
    int rt = node >> 4, r = node & 15;
    Ap2[(size_t)(rt * 8 + kt) * 64 + g * 16 + r] = o;
  }
}

// ------- fused aggregation, mu & logstd: one wave/node, single online pass -------
// slot = lane>>4 (4 slots), branch = (lane>>3)&1, octet = lane&7
__global__ __launch_bounds__(256)
void gat_aggr2_k(const int* __restrict__ offs, const int* __restrict__ srcs,
                 const float* __restrict__ as2m, const float* __restrict__ ad2m,
                 const float* __restrict__ as2l, const float* __restrict__ ad2l,
                 const bf16* __restrict__ hmu, const bf16* __restrict__ hls,
                 const float* __restrict__ bmu, const float* __restrict__ bls,
                 float* __restrict__ outmu, float* __restrict__ outls, int n){
  int node = blockIdx.x * 4 + (threadIdx.x >> 6);
  if (node >= n) return;
  int lane = threadIdx.x & 63;
  int beg = offs[node], end = offs[node + 1];
  int br   = (lane >> 3) & 1;
  int oct  = lane & 7;
  int slot = lane >> 4;
  const float* asP = br ? as2l : as2m;
  float advP = (br ? ad2l : ad2m)[node];
  const bf16* hP = br ? hls : hmu;
  float m = -1e30f, s = 0.f;
  float acc[8];
  #pragma unroll
  for (int i = 0; i < 8; i++) acc[i] = 0.f;
  #pragma unroll 4
  for (int j0 = beg; j0 < end; j0 += 4){
    int j = j0 + slot;
    if (j < end){
      int si = srcs[j];
      float e = lrelu(asP[si] + advP);
      float p;
      if (e > m){
        float f = __expf(m - e);
        s = s * f + 1.f;
        #pragma unroll
        for (int i = 0; i < 8; i++) acc[i] *= f;
        m = e; p = 1.f;
      } else {
        p = __expf(e - m);
        s += p;
      }
      uint4 dw = *(const uint4*)(hP + (size_t)si * 64 + oct * 8);
      float lo, hi;
      unpack2(dw.x, lo, hi); acc[0] = fmaf(lo, p, acc[0]); acc[1] = fmaf(hi, p, acc[1]);
      unpack2(dw.y, lo, hi); acc[2] = fmaf(lo, p, acc[2]); acc[3] = fmaf(hi, p, acc[3]);
      unpack2(dw.z, lo, hi); acc[4] = fmaf(lo, p, acc[4]); acc[5] = fmaf(hi, p, acc[5]);
      unpack2(dw.w, lo, hi); acc[6] = fmaf(lo, p, acc[6]); acc[7] = fmaf(hi, p, acc[7]);
    }
  }
  #pragma unroll
  for (int off = 16; off <= 32; off <<= 1){
    float mo = __shfl_xor(m, off);
    float so = __shfl_xor(s, off);
    float nm = fmaxf(m, mo);
    float f  = __expf(m - nm);
    float fo = __expf(mo - nm);
    s = s * f + so * fo;
    #pragma unroll
    for (int i = 0; i < 8; i++)
      acc[i] = acc[i] * f + __shfl_xor(acc[i], off) * fo;
    m = nm;
  }
  if (lane < 16){
    float inv = 1.f / (s + 1e-16f);
    const float* bb = (lane >= 8) ? bls : bmu;
    float* out = (lane >= 8) ? outls : outmu;
    float v[8];
    #pragma unroll
    for (int i = 0; i < 8; i++) v[i] = acc[i] * inv + bb[oct * 8 + i];
    float* op = out + (size_t)node * 64 + oct * 8;
    *(float4*)op       = make_float4(v[0], v[1], v[2], v[3]);
    *(float4*)(op + 4) = make_float4(v[4], v[5], v[6], v[7]);
  }
}

extern "C" void kernel_launch(void* const* d_in, const int* in_sizes, int n_in,
                              void* d_out, int out_size, void* d_ws, size_t ws_size,
                              hipStream_t stream){
  const float* x    = (const float*)d_in[0];
  const int*   ei   = (const int*)d_in[1];
  const float* W1   = (const float*)d_in[2];
  const float* aS1  = (const float*)d_in[3];
  const float* aD1  = (const float*)d_in[4];
  const float* b1   = (const float*)d_in[5];
  const float* Wmu  = (const float*)d_in[6];
  const float* aSmu = (const float*)d_in[7];
  const float* aDmu = (const float*)d_in[8];
  const float* bmu  = (const float*)d_in[9];
  const float* Wls  = (const float*)d_in[10];
  const float* aSls = (const float*)d_in[11];
  const float* aDls = (const float*)d_in[12];
  const float* bls  = (const float*)d_in[13];

  const int N    = NNODES;
  const int E0   = in_sizes[1] / 2;
  const int Etot = E0 + N;

  // ---- workspace layout (float-unit offsets; bf16x8 arrays 16B-aligned) ----
  float* ws = (float*)d_ws;
  bf16x8* Ap2  = (bf16x8*)(ws);                 // [0, 6.4M): layer-1 out, packed A-frag
  bf16*   h1bf = (bf16*)(ws + 6400000);         // [6.4M, 12.8M): 12.8M bf16 row-major
  bf16*   h2mu = (bf16*)(ws + 12800000);        // [12.8M, 14.4M)
  bf16*   h2ls = (bf16*)(ws + 14400000);        // [14.4M, 16M)
  float*  as1  = ws + 16000000;                 // 200K
  float*  ad1  = ws + 16200000;                 // 200K
  float*  as2m = ws + 16400000;                 // 50K each
  float*  ad2m = ws + 16450000;
  float*  as2l = ws + 16500000;
  float*  ad2l = ws + 16550000;
  int*      offs  = (int*)(ws + 16600000);      // 50001
  int*      srcs  = (int*)(ws + 16650016);      // 850000
  unsigned* buck  = (unsigned*)(ws + 17500016); // 850000
  int*      bcnt  = (int*)(ws + 18350016);      // 256
  int*      bbase = (int*)(ws + 18350272);      // 257
  int*      bcur  = (int*)(ws + 18350544);      // 256
  bf16x8*   Bp1   = (bf16x8*)(ws + 18351040);   // 32768 bf16 (16B-aligned)
  bf16x8*   Bp2   = (bf16x8*)(ws + 18367424);   // 32768 bf16

  float* outmu = (float*)d_out;
  float* outls = (float*)d_out + 3200000;

  const int egrid4 = (Etot + 1023) / 1024;

  // ---- CSR build: two-phase LDS bucket sort ----
  hipMemsetAsync(bcnt, 0, 256 * sizeof(int), stream);
  bhist_k<<<egrid4, 256, 0, stream>>>(ei, E0, Etot, bcnt);
  bscan_k<<<1, 256, 0, stream>>>(bcnt, bbase, bcur, Etot);
  bscat_k<<<egrid4, 256, 0, stream>>>(ei, E0, Etot, bcur, buck);
  bcsr_k<<<NB, 256, 0, stream>>>(buck, bbase, offs, srcs, N);

  // ---- weight packing for MFMA ----
  cvt_w_k<<<32, 256, 0, stream>>>(W1, Wmu, Wls, Bp1, Bp2);

  // ---- layer 1: GATConv(128 -> 4x64, concat) + bias + ReLU ----
  gemm1_mfma<<<MT, 256, 0, stream>>>(x, Bp1, aS1, aD1, h1bf, as1, ad1);
  gat_aggr1_k<<<(N + 3) / 4, 256, 0, stream>>>(offs, srcs, as1, ad1, h1bf, b1, Ap2, N);

  // ---- layers mu & logstd: GATConv(256 -> 1x64) + bias ----
  gemm2_mfma<<<(MT + 3) / 4, 256, 0, stream>>>(Ap2, Bp2, aSmu, aDmu, aSls, aDls,
                                               h2mu, h2ls, as2m, ad2m, as2l, ad2l);
  gat_aggr2_k<<<(N + 3) / 4, 256, 0, stream>>>(offs, srcs, as2m, ad2m, as2l, ad2l,
                                               h2mu, h2ls, bmu, bls, outmu, outls, N);
}

// Round 12
// 231.522 us; speedup vs baseline: 1.3605x; 1.0422x over previous
//
#include <hip/hip_runtime.h>
#include <hip/hip_bf16.h>

#define NNODES 50000
#define MT 3125              // NNODES / 16 row-tiles
#define NB 196               // ceil(NNODES / 256) dst-buckets
typedef __hip_bfloat16 bf16;
typedef __attribute__((ext_vector_type(8))) short bf16x8;  // 8 bf16 (4 VGPRs)
typedef __attribute__((ext_vector_type(4))) float f32x4;   // 4 f32 acc

__device__ __forceinline__ void unpack2(unsigned w, float& lo, float& hi){
  lo = __uint_as_float(w << 16);
  hi = __uint_as_float(w & 0xffff0000u);
}
__device__ __forceinline__ short f2bf(float f){
  union { __hip_bfloat16 h; short s; } u; u.h = __float2bfloat16(f); return u.s;
}
__device__ __forceinline__ float lrelu(float v){ return v > 0.f ? v : 0.2f * v; }

// ---------------- pack weights -> B-fragment bf16 ----------------
__global__ __launch_bounds__(256)
void cvt_w_k(const float* __restrict__ W1, const float* __restrict__ Wmu,
             const float* __restrict__ Wls, bf16x8* __restrict__ Bp1,
             bf16x8* __restrict__ Bp2){
  int t = blockIdx.x * 256 + threadIdx.x;
  if (t < 4096){
    int lane = t & 63, ct = (t >> 6) & 15, kt = t >> 10;
    int k0 = kt * 32 + (lane >> 4) * 8, col = ct * 16 + (lane & 15);
    bf16x8 o;
    #pragma unroll
    for (int j = 0; j < 8; j++) o[j] = f2bf(W1[(size_t)(k0 + j) * 256 + col]);
    Bp1[t] = o;
  } else if (t < 8192){
    int u = t - 4096;
    int lane = u & 63, ct = (u >> 6) & 7, kt = u >> 9;
    int k0 = kt * 32 + (lane >> 4) * 8, col = ct * 16 + (lane & 15);
    const float* W = (col < 64) ? Wmu : Wls;
    int cc = col & 63;
    bf16x8 o;
    #pragma unroll
    for (int j = 0; j < 8; j++) o[j] = f2bf(W[(size_t)(k0 + j) * 64 + cc]);
    Bp2[u] = o;
  }
}

// ------- MFMA GEMM 1 (reads f32 x directly) + fused alpha -------
__global__ __launch_bounds__(256)
void gemm1_mfma(const float* __restrict__ x, const bf16x8* __restrict__ Bp,
                const float* __restrict__ aS, const float* __restrict__ aD,
                bf16* __restrict__ Y, float* __restrict__ as1, float* __restrict__ ad1){
  int rt = blockIdx.x;
  int w = threadIdx.x >> 6, lane = threadIdx.x & 63;
  const float* xr = x + (size_t)(rt * 16 + (lane & 15)) * 128 + (lane >> 4) * 8;
  f32x4 z = {0.f, 0.f, 0.f, 0.f};
  f32x4 acc[4] = {z, z, z, z};
  for (int kt = 0; kt < 4; kt++){
    float4 v0 = *(const float4*)(xr + kt * 32);
    float4 v1 = *(const float4*)(xr + kt * 32 + 4);
    bf16x8 a;
    a[0] = f2bf(v0.x); a[1] = f2bf(v0.y); a[2] = f2bf(v0.z); a[3] = f2bf(v0.w);
    a[4] = f2bf(v1.x); a[5] = f2bf(v1.y); a[6] = f2bf(v1.z); a[7] = f2bf(v1.w);
    #pragma unroll
    for (int c = 0; c < 4; c++){
      bf16x8 b = Bp[(size_t)(kt * 16 + w * 4 + c) * 64 + lane];
      acc[c] = __builtin_amdgcn_mfma_f32_16x16x32_bf16(a, b, acc[c], 0, 0, 0);
    }
  }
  int row0 = rt * 16 + (lane >> 4) * 4;
  #pragma unroll
  for (int c = 0; c < 4; c++){
    int col = w * 64 + c * 16 + (lane & 15);
    #pragma unroll
    for (int i = 0; i < 4; i++)
      Y[(size_t)(row0 + i) * 256 + col] = __float2bfloat16(acc[c][i]);
  }
  float aSv[4], aDv[4];
  #pragma unroll
  for (int c = 0; c < 4; c++){
    int col = c * 16 + (lane & 15);
    aSv[c] = aS[w * 64 + col];
    aDv[c] = aD[w * 64 + col];
  }
  #pragma unroll
  for (int i = 0; i < 4; i++){
    float s1 = 0.f, s2 = 0.f;
    #pragma unroll
    for (int c = 0; c < 4; c++){
      s1 = fmaf(acc[c][i], aSv[c], s1);
      s2 = fmaf(acc[c][i], aDv[c], s2);
    }
    #pragma unroll
    for (int o = 1; o < 16; o <<= 1){
      s1 += __shfl_xor(s1, o);
      s2 += __shfl_xor(s2, o);
    }
    if ((lane & 15) == 0){
      int node = row0 + i;
      as1[node * 4 + w] = s1;
      ad1[node * 4 + w] = s2;
    }
  }
}

// ------- MFMA GEMM 2: one wave = one row-tile, BOTH branches + fused alphas -------
__global__ __launch_bounds__(256)
void gemm2_mfma(const bf16x8* __restrict__ Ap, const bf16x8* __restrict__ Bp,
                const float* __restrict__ aSmu, const float* __restrict__ aDmu,
                const float* __restrict__ aSls, const float* __restrict__ aDls,
                bf16* __restrict__ Ymu, bf16* __restrict__ Yls,
                float* __restrict__ as2m, float* __restrict__ ad2m,
                float* __restrict__ as2l, float* __restrict__ ad2l){
  int w = threadIdx.x >> 6, lane = threadIdx.x & 63;
  int rt = blockIdx.x * 4 + w;
  if (rt >= MT) return;
  f32x4 z = {0.f, 0.f, 0.f, 0.f};
  f32x4 acc[8] = {z, z, z, z, z, z, z, z};   // 0-3 mu, 4-7 ls
  for (int kt = 0; kt < 8; kt++){
    bf16x8 a = Ap[(size_t)(rt * 8 + kt) * 64 + lane];
    #pragma unroll
    for (int c = 0; c < 8; c++){
      bf16x8 b = Bp[(size_t)(kt * 8 + c) * 64 + lane];
      acc[c] = __builtin_amdgcn_mfma_f32_16x16x32_bf16(a, b, acc[c], 0, 0, 0);
    }
  }
  int row0 = rt * 16 + (lane >> 4) * 4;
  #pragma unroll
  for (int c = 0; c < 4; c++){
    int col = c * 16 + (lane & 15);
    #pragma unroll
    for (int i = 0; i < 4; i++){
      Ymu[(size_t)(row0 + i) * 64 + col] = __float2bfloat16(acc[c][i]);
      Yls[(size_t)(row0 + i) * 64 + col] = __float2bfloat16(acc[4 + c][i]);
    }
  }
  float aSm[4], aDm[4], aSl[4], aDl[4];
  #pragma unroll
  for (int c = 0; c < 4; c++){
    int col = c * 16 + (lane & 15);
    aSm[c] = aSmu[col]; aDm[c] = aDmu[col];
    aSl[c] = aSls[col]; aDl[c] = aDls[col];
  }
  #pragma unroll
  for (int i = 0; i < 4; i++){
    float s1 = 0.f, s2 = 0.f, s3 = 0.f, s4 = 0.f;
    #pragma unroll
    for (int c = 0; c < 4; c++){
      s1 = fmaf(acc[c][i], aSm[c], s1);
      s2 = fmaf(acc[c][i], aDm[c], s2);
      s3 = fmaf(acc[4 + c][i], aSl[c], s3);
      s4 = fmaf(acc[4 + c][i], aDl[c], s4);
    }
    #pragma unroll
    for (int o = 1; o < 16; o <<= 1){
      s1 += __shfl_xor(s1, o);
      s2 += __shfl_xor(s2, o);
      s3 += __shfl_xor(s3, o);
      s4 += __shfl_xor(s4, o);
    }
    if ((lane & 15) == 0){
      int node = row0 + i;
      as2m[node] = s1; ad2m[node] = s2;
      as2l[node] = s3; ad2l[node] = s4;
    }
  }
}

// ================ two-phase LDS bucket CSR build ================
__global__ __launch_bounds__(256)
void bhist_k(const int* __restrict__ ei, int E0, int Etot, int* __restrict__ bcnt){
  __shared__ int lh[NB];
  for (int i = threadIdx.x; i < NB; i += 256) lh[i] = 0;
  __syncthreads();
  int base = blockIdx.x * 1024 + threadIdx.x;
  #pragma unroll
  for (int q = 0; q < 4; q++){
    int e = base + q * 256;
    if (e < Etot){
      int d = (e < E0) ? ei[E0 + e] : e - E0;
      atomicAdd(&lh[d >> 8], 1);
    }
  }
  __syncthreads();
  for (int i = threadIdx.x; i < NB; i += 256)
    if (lh[i]) atomicAdd(&bcnt[i], lh[i]);
}

__global__ __launch_bounds__(256)
void bscan_k(const int* __restrict__ bcnt, int* __restrict__ bbase,
             int* __restrict__ bcur, int total){
  __shared__ int buf[256];
  int t = threadIdx.x;
  int v = (t < NB) ? bcnt[t] : 0;
  buf[t] = v; __syncthreads();
  int acc = v;
  for (int off = 1; off < 256; off <<= 1){
    int x = (t >= off) ? buf[t - off] : 0;
    __syncthreads();
    acc += x; buf[t] = acc; __syncthreads();
  }
  if (t < NB){ int ex = acc - v; bbase[t] = ex; bcur[t] = ex; }
  if (t == 0) bbase[NB] = total;
}

__global__ __launch_bounds__(256)
void bscat_k(const int* __restrict__ ei, int E0, int Etot,
             int* __restrict__ bcur, unsigned* __restrict__ buck){
  __shared__ int lh[NB];
  __shared__ int lbase[NB];
  for (int i = threadIdx.x; i < NB; i += 256) lh[i] = 0;
  __syncthreads();
  int base = blockIdx.x * 1024 + threadIdx.x;
  int sA[4], dA[4], rA[4];
  #pragma unroll
  for (int q = 0; q < 4; q++){
    int e = base + q * 256;
    sA[q] = -1;
    if (e < Etot){
      int s, d;
      if (e < E0){ s = ei[e]; d = ei[E0 + e]; } else { s = d = e - E0; }
      sA[q] = s; dA[q] = d;
      rA[q] = atomicAdd(&lh[d >> 8], 1);
    }
  }
  __syncthreads();
  for (int i = threadIdx.x; i < NB; i += 256)
    lbase[i] = lh[i] ? atomicAdd(&bcur[i], lh[i]) : 0;
  __syncthreads();
  #pragma unroll
  for (int q = 0; q < 4; q++){
    if (sA[q] >= 0){
      int bk = dA[q] >> 8;
      buck[lbase[bk] + rA[q]] = ((unsigned)(dA[q] & 255) << 16) | (unsigned)sA[q];
    }
  }
}

__global__ __launch_bounds__(256)
void bcsr_k(const unsigned* __restrict__ buck, const int* __restrict__ bbase,
            int* __restrict__ offs, int* __restrict__ srcs, int n){
  int b = blockIdx.x;
  int lo = bbase[b], hi = bbase[b + 1];
  __shared__ int eh[256];
  __shared__ int buf[256];
  int t = threadIdx.x;
  eh[t] = 0;
  __syncthreads();
  for (int j = lo + t; j < hi; j += 256)
    atomicAdd(&eh[(buck[j] >> 16) & 255], 1);
  __syncthreads();
  int v = eh[t];
  buf[t] = v; __syncthreads();
  int acc = v;
  for (int off = 1; off < 256; off <<= 1){
    int x = (t >= off) ? buf[t - off] : 0;
    __syncthreads();
    acc += x; buf[t] = acc; __syncthreads();
  }
  int loff = acc - v;   // exclusive within bucket
  int node = b * 256 + t;
  if (node < n) offs[node] = lo + loff;
  if (b == NB - 1 && t == 0) offs[n] = bbase[NB];
  __syncthreads();
  eh[t] = loff;        // reuse as cursors
  __syncthreads();
  for (int j = lo + t; j < hi; j += 256){
    unsigned val = buck[j];
    int dlo = (val >> 16) & 255;
    int rank = atomicAdd(&eh[dlo], 1);
    srcs[lo + rank] = (int)(val & 0xffffu);
  }
}

// ------- aggregation layer 1: 2 nodes/block, precomputed max, parallel pass 2 -------
// passA: head = lane>>4, idx = lane&15 -> m per head (as table is L2-hot)
// pass2: slot = lane>>5 (2), head = (lane>>3)&3, oct = lane&7; p=exp(e-m), s+=p
__global__ __launch_bounds__(128)
void gat_aggr1_k(const int* __restrict__ offs, const int* __restrict__ srcs,
                 const float* __restrict__ as, const float* __restrict__ ad,
                 const bf16* __restrict__ h, const float* __restrict__ b,
                 bf16x8* __restrict__ Ap2, int n){
  int node = blockIdx.x * 2 + (threadIdx.x >> 6);
  if (node >= n) return;
  int lane = threadIdx.x & 63;
  int beg = offs[node], end = offs[node + 1];
  int hA = lane >> 4, iA = lane & 15;
  float advA = ad[node * 4 + hA];
  float m = -1e30f;
  for (int j = beg + iA; j < end; j += 16)
    m = fmaxf(m, lrelu(as[srcs[j] * 4 + hA] + advA));
  #pragma unroll
  for (int o = 1; o < 16; o <<= 1) m = fmaxf(m, __shfl_xor(m, o));
  int hP = (lane >> 3) & 3, oct = lane & 7, slot = lane >> 5;
  float mP   = __shfl(m, hP * 16);
  float advP = __shfl(advA, hP * 16);
  float s = 0.f;
  float acc[8];
  #pragma unroll
  for (int i = 0; i < 8; i++) acc[i] = 0.f;
  #pragma unroll 8
  for (int j0 = beg; j0 < end; j0 += 2){
    int j = j0 + slot;
    if (j < end){
      int si = srcs[j];
      float e = lrelu(as[si * 4 + hP] + advP);
      float p = __expf(e - mP);
      s += p;
      uint4 dw = *(const uint4*)(h + (size_t)si * 256 + hP * 64 + oct * 8);
      float lo, hi;
      unpack2(dw.x, lo, hi); acc[0] = fmaf(lo, p, acc[0]); acc[1] = fmaf(hi, p, acc[1]);
      unpack2(dw.y, lo, hi); acc[2] = fmaf(lo, p, acc[2]); acc[3] = fmaf(hi, p, acc[3]);
      unpack2(dw.z, lo, hi); acc[4] = fmaf(lo, p, acc[4]); acc[5] = fmaf(hi, p, acc[5]);
      unpack2(dw.w, lo, hi); acc[6] = fmaf(lo, p, acc[6]); acc[7] = fmaf(hi, p, acc[7]);
    }
  }
  s += __shfl_xor(s, 32);
  #pragma unroll
  for (int i = 0; i < 8; i++) acc[i] += __shfl_xor(acc[i], 32);
  if (lane < 32){
    float inv = 1.f / (s + 1e-16f);
    bf16x8 o;
    #pragma unroll
    for (int i = 0; i < 8; i++){
      float vv = acc[i] * inv + b[lane * 8 + i];
      o[i] = f2bf(vv > 0.f ? vv : 0.f);
    }
    int kt = lane >> 2, g = lane & 3;
    int rt = node >> 4, r = node & 15;
    Ap2[(size_t)(rt * 8 + kt) * 64 + g * 16 + r] = o;
  }
}

// ------- aggregation mu & logstd: 2 nodes/block, precomputed max, parallel pass 2 -------
// passA: branch = lane>>5, idx = lane&31 -> m per branch
// pass2: slot = lane>>4 (4), branch = (lane>>3)&1, oct = lane&7
__global__ __launch_bounds__(128)
void gat_aggr2_k(const int* __restrict__ offs, const int* __restrict__ srcs,
                 const float* __restrict__ as2m, const float* __restrict__ ad2m,
                 const float* __restrict__ as2l, const float* __restrict__ ad2l,
                 const bf16* __restrict__ hmu, const bf16* __restrict__ hls,
                 const float* __restrict__ bmu, const float* __restrict__ bls,
                 float* __restrict__ outmu, float* __restrict__ outls, int n){
  int node = blockIdx.x * 2 + (threadIdx.x >> 6);
  if (node >= n) return;
  int lane = threadIdx.x & 63;
  int beg = offs[node], end = offs[node + 1];
  const float* asA = (lane >= 32) ? as2l : as2m;
  float advA = ((lane >= 32) ? ad2l : ad2m)[node];
  int iA = lane & 31;
  float m = -1e30f;
  for (int j = beg + iA; j < end; j += 32)
    m = fmaxf(m, lrelu(asA[srcs[j]] + advA));
  #pragma unroll
  for (int o = 1; o < 32; o <<= 1) m = fmaxf(m, __shfl_xor(m, o));
  int br = (lane >> 3) & 1, oct = lane & 7, slot = lane >> 4;
  float mP   = __shfl(m, br * 32);
  float advP = __shfl(advA, br * 32);
  const float* asP = br ? as2l : as2m;
  const bf16*  hP  = br ? hls : hmu;
  float s = 0.f;
  float acc[8];
  #pragma unroll
  for (int i = 0; i < 8; i++) acc[i] = 0.f;
  #pragma unroll 4
  for (int j0 = beg; j0 < end; j0 += 4){
    int j = j0 + slot;
    if (j < end){
      int si = srcs[j];
      float e = lrelu(asP[si] + advP);
      float p = __expf(e - mP);
      s += p;
      uint4 dw = *(const uint4*)(hP + (size_t)si * 64 + oct * 8);
      float lo, hi;
      unpack2(dw.x, lo, hi); acc[0] = fmaf(lo, p, acc[0]); acc[1] = fmaf(hi, p, acc[1]);
      unpack2(dw.y, lo, hi); acc[2] = fmaf(lo, p, acc[2]); acc[3] = fmaf(hi, p, acc[3]);
      unpack2(dw.z, lo, hi); acc[4] = fmaf(lo, p, acc[4]); acc[5] = fmaf(hi, p, acc[5]);
      unpack2(dw.w, lo, hi); acc[6] = fmaf(lo, p, acc[6]); acc[7] = fmaf(hi, p, acc[7]);
    }
  }
  #pragma unroll
  for (int off = 16; off <= 32; off <<= 1){
    s += __shfl_xor(s, off);
    #pragma unroll
    for (int i = 0; i < 8; i++) acc[i] += __shfl_xor(acc[i], off);
  }
  if (lane < 16){
    float inv = 1.f / (s + 1e-16f);
    const float* bb = (lane >= 8) ? bls : bmu;
    float* out = (lane >= 8) ? outls : outmu;
    float v[8];
    #pragma unroll
    for (int i = 0; i < 8; i++) v[i] = acc[i] * inv + bb[oct * 8 + i];
    float* op = out + (size_t)node * 64 + oct * 8;
    *(float4*)op       = make_float4(v[0], v[1], v[2], v[3]);
    *(float4*)(op + 4) = make_float4(v[4], v[5], v[6], v[7]);
  }
}

extern "C" void kernel_launch(void* const* d_in, const int* in_sizes, int n_in,
                              void* d_out, int out_size, void* d_ws, size_t ws_size,
                              hipStream_t stream){
  const float* x    = (const float*)d_in[0];
  const int*   ei   = (const int*)d_in[1];
  const float* W1   = (const float*)d_in[2];
  const float* aS1  = (const float*)d_in[3];
  const float* aD1  = (const float*)d_in[4];
  const float* b1   = (const float*)d_in[5];
  const float* Wmu  = (const float*)d_in[6];
  const float* aSmu = (const float*)d_in[7];
  const float* aDmu = (const float*)d_in[8];
  const float* bmu  = (const float*)d_in[9];
  const float* Wls  = (const float*)d_in[10];
  const float* aSls = (const float*)d_in[11];
  const float* aDls = (const float*)d_in[12];
  const float* bls  = (const float*)d_in[13];

  const int N    = NNODES;
  const int E0   = in_sizes[1] / 2;
  const int Etot = E0 + N;

  // ---- workspace layout (float-unit offsets; bf16x8 arrays 16B-aligned) ----
  float* ws = (float*)d_ws;
  bf16x8* Ap2  = (bf16x8*)(ws);                 // [0, 6.4M): layer-1 out, packed A-frag
  bf16*   h1bf = (bf16*)(ws + 6400000);         // [6.4M, 12.8M): 12.8M bf16 row-major
  bf16*   h2mu = (bf16*)(ws + 12800000);        // [12.8M, 14.4M)
  bf16*   h2ls = (bf16*)(ws + 14400000);        // [14.4M, 16M)
  float*  as1  = ws + 16000000;                 // 200K
  float*  ad1  = ws + 16200000;                 // 200K
  float*  as2m = ws + 16400000;                 // 50K each
  float*  ad2m = ws + 16450000;
  float*  as2l = ws + 16500000;
  float*  ad2l = ws + 16550000;
  int*      offs  = (int*)(ws + 16600000);      // 50001
  int*      srcs  = (int*)(ws + 16650016);      // 850000
  unsigned* buck  = (unsigned*)(ws + 17500016); // 850000
  int*      bcnt  = (int*)(ws + 18350016);      // 256
  int*      bbase = (int*)(ws + 18350272);      // 257
  int*      bcur  = (int*)(ws + 18350544);      // 256
  bf16x8*   Bp1   = (bf16x8*)(ws + 18351040);   // 32768 bf16 (16B-aligned)
  bf16x8*   Bp2   = (bf16x8*)(ws + 18367424);   // 32768 bf16

  float* outmu = (float*)d_out;
  float* outls = (float*)d_out + 3200000;

  const int egrid4 = (Etot + 1023) / 1024;

  // ---- CSR build: two-phase LDS bucket sort ----
  hipMemsetAsync(bcnt, 0, 256 * sizeof(int), stream);
  bhist_k<<<egrid4, 256, 0, stream>>>(ei, E0, Etot, bcnt);
  bscan_k<<<1, 256, 0, stream>>>(bcnt, bbase, bcur, Etot);
  bscat_k<<<egrid4, 256, 0, stream>>>(ei, E0, Etot, bcur, buck);
  bcsr_k<<<NB, 256, 0, stream>>>(buck, bbase, offs, srcs, N);

  // ---- weight packing for MFMA ----
  cvt_w_k<<<32, 256, 0, stream>>>(W1, Wmu, Wls, Bp1, Bp2);

  // ---- layer 1: GATConv(128 -> 4x64, concat) + bias + ReLU ----
  gemm1_mfma<<<MT, 256, 0, stream>>>(x, Bp1, aS1, aD1, h1bf, as1, ad1);
  gat_aggr1_k<<<(N + 1) / 2, 128, 0, stream>>>(offs, srcs, as1, ad1, h1bf, b1, Ap2, N);

  // ---- layers mu & logstd: GATConv(256 -> 1x64) + bias ----
  gemm2_mfma<<<(MT + 3) / 4, 256, 0, stream>>>(Ap2, Bp2, aSmu, aDmu, aSls, aDls,
                                               h2mu, h2ls, as2m, ad2m, as2l, ad2l);
  gat_aggr2_k<<<(N + 1) / 2, 128, 0, stream>>>(offs, srcs, as2m, ad2m, as2l, ad2l,
                                               h2mu, h2ls, bmu, bls, outmu, outls, N);
}